// Round 8
// baseline (111.685 us; speedup 1.0000x reference)
//
#include <hip/hip_runtime.h>

// RoPEAttention MI355X round 21:
//  attn: T12 in-register softmax, NO inline asm (r20 failed; suspects were the
//        two asm ops). Pack via bf16x2 + bit_cast; half-exchange via shfl_xor 32.
//        Routing: lane (b1=lg>>1,b0=lg&1) sends pw[2kc + !b1... ] == b1?pw[2kc]
//        :pw[2kc+1]; selects recv iff b1!=b0. Ps LDS deleted -> 32KB LDS.
//  qkv : r19 192x128 (CLOSED). proj/prep: unchanged (110.3us base).

typedef __bf16 bf16;
typedef __bf16 bf16x2 __attribute__((ext_vector_type(2)));
typedef __bf16 bf16x4 __attribute__((ext_vector_type(4)));
typedef __bf16 bf16x8 __attribute__((ext_vector_type(8)));
typedef float f32x4 __attribute__((ext_vector_type(4)));
typedef unsigned int u32x4 __attribute__((ext_vector_type(4)));

namespace {
constexpr int kC = 768;
constexpr int kNtok = 577;
constexpr int kM = 16 * kNtok;     // 9232
constexpr int kMpadQ = 9408;       // 49 * 192 (qkv A pad)
constexpr int kMpadP = 9344;       // 73 * 128 (proj A pad)
constexpr int kTok = 640;
constexpr int kBH = 192;
}

typedef __attribute__((address_space(3))) unsigned int as3_u32;
typedef __attribute__((address_space(1))) unsigned int as1_u32;
__device__ __forceinline__ void gl16(const bf16* g, bf16* l) {
  __builtin_amdgcn_global_load_lds((const as1_u32*)g, (as3_u32*)l, 16, 0, 0);
}

// m204 bijective XCD swizzle
__device__ __forceinline__ int swz_lid(int hid, int nwg) {
  int q = nwg >> 3, r = nwg & 7;
  int x = hid & 7, y = hid >> 3;
  int base = (x < r) ? x * (q + 1) : r * (q + 1) + (x - r) * q;
  return base + y;
}

// ---------------- fused prep: conv_x | conv_w(qkv) | conv_w(proj) | rope --------
__global__ __launch_bounds__(256) void prep_kernel(
    const float* __restrict__ x, const float* __restrict__ qkv_w,
    const float* __restrict__ proj_w, const float* __restrict__ freqs,
    bf16* __restrict__ xb, bf16* __restrict__ wqb, bf16* __restrict__ pwb,
    float* __restrict__ cosT, float* __restrict__ sinT) {
  const int bidx = (int)blockIdx.x;
  const int tid = (int)threadIdx.x;
  if (bidx < 3528) {                       // conv_x: kMpadQ*96 chunks of 8
    int idx = bidx * 256 + tid;
    int m = idx / 96, c8 = (idx % 96) * 8;
    bf16x8 o;
    if (m < kM) {
      const float* p = x + (size_t)m * kC + c8;
#pragma unroll
      for (int j = 0; j < 8; ++j) o[j] = (bf16)p[j];
    } else {
#pragma unroll
      for (int j = 0; j < 8; ++j) o[j] = (bf16)0.0f;
    }
    *(bf16x8*)(xb + (size_t)m * kC + c8) = o;
  } else if (bidx < 3528 + 864) {          // conv_w qkv: 2304*768
    int off = ((bidx - 3528) * 256 + tid) * 8;
    bf16x8 o;
#pragma unroll
    for (int j = 0; j < 8; ++j) o[j] = (bf16)qkv_w[off + j];
    *(bf16x8*)(wqb + off) = o;
  } else if (bidx < 3528 + 864 + 288) {    // conv_w proj: 768*768
    int off = ((bidx - 3528 - 864) * 256 + tid) * 8;
    bf16x8 o;
#pragma unroll
    for (int j = 0; j < 8; ++j) o[j] = (bf16)proj_w[off + j];
    *(bf16x8*)(pwb + off) = o;
  } else {                                 // rope table: 12*576*32
    int idx = (bidx - 3528 - 864 - 288) * 256 + tid;
    int f = idx & 31;
    int t = (idx >> 5) % 576;
    int h = idx / (576 * 32);
    float ang = (float)(t % 24) * freqs[h * 32 + f] + (float)(t / 24) * freqs[384 + h * 32 + f];
    float s, c;
    sincosf(ang, &s, &c);
    cosT[idx] = c;
    sinT[idx] = s;
  }
}

// ---------------- qkv GEMM 192x128, 8 waves (4M x 2N, wave 48x64), BK=64 --------
__global__ __launch_bounds__(512, 4) void qkv_gemm_kernel(
    const bf16* __restrict__ xb, const bf16* __restrict__ wb,
    const float* __restrict__ cosT, const float* __restrict__ sinT,
    bf16* __restrict__ qh, bf16* __restrict__ kbq, bf16* __restrict__ vtb) {
  __shared__ __align__(16) char smem[81920];
  bf16* AsB = (bf16*)smem;             // [2][192*64] = 48 KB
  bf16* BsB = (bf16*)(smem + 49152);   // [2][128*64] = 32 KB
  const int tid = (int)threadIdx.x;
  const int l = tid & 63, w = tid >> 6;        // 8 waves
  const int lr = l & 15, lg = l >> 4;
  const int wr = (w & 3) * 48, wc = (w >> 2) * 64;   // wave tile 48x64

  const int lid = swz_lid((int)blockIdx.x, 49 * 18);
  const int n0 = (lid % 18) * 128, m0 = (lid / 18) * 192;

  const int srow = w * 8 + (l >> 3);           // 64 rows per staging pass
  const int gch = (l & 7) ^ ((l >> 3) & 7);    // pre-swizzled global chunk
  const bf16* aG = xb + (size_t)(m0 + srow) * kC + gch * 8;
  const bf16* bG = wb + (size_t)(n0 + srow) * kC + gch * 8;

  f32x4 acc[3][4];
  const f32x4 z = {0.f, 0.f, 0.f, 0.f};
#pragma unroll
  for (int mi = 0; mi < 3; ++mi)
#pragma unroll
    for (int ni = 0; ni < 4; ++ni) acc[mi][ni] = z;

  auto STAGE = [&](int buf, int k0) {
#pragma unroll
    for (int i = 0; i < 3; ++i)
      gl16(aG + (size_t)i * 64 * kC + k0, &AsB[buf * 12288 + (i * 64 + w * 8) * 64]);
#pragma unroll
    for (int j = 0; j < 2; ++j)
      gl16(bG + (size_t)j * 64 * kC + k0, &BsB[buf * 8192 + (j * 64 + w * 8) * 64]);
  };
  auto COMPUTE = [&](int buf) {
    __builtin_amdgcn_s_setprio(1);
#pragma unroll
    for (int kc = 0; kc < 2; ++kc) {
      bf16x8 af[3], bfr[4];
#pragma unroll
      for (int ni = 0; ni < 4; ++ni) {
        int row = wc + ni * 16 + lr;
        bfr[ni] = *(const bf16x8*)&BsB[buf * 8192 + row * 64 + (((kc * 4 + lg) ^ (lr & 7)) << 3)];
      }
#pragma unroll
      for (int mi = 0; mi < 3; ++mi) {
        int row = wr + mi * 16 + lr;
        af[mi] = *(const bf16x8*)&AsB[buf * 12288 + row * 64 + (((kc * 4 + lg) ^ (lr & 7)) << 3)];
      }
#pragma unroll
      for (int mi = 0; mi < 3; ++mi)
#pragma unroll
        for (int ni = 0; ni < 4; ++ni)
          acc[mi][ni] = __builtin_amdgcn_mfma_f32_16x16x32_bf16(af[mi], bfr[ni], acc[mi][ni], 0, 0, 0);
    }
    __builtin_amdgcn_s_setprio(0);
  };

  STAGE(0, 0);
#pragma unroll 1
  for (int t = 0; t < 11; ++t) {
    const int buf = t & 1;
    STAGE(buf ^ 1, (t + 1) * 64);
    asm volatile("s_waitcnt vmcnt(5)" ::: "memory");
    __builtin_amdgcn_sched_barrier(0);
    __builtin_amdgcn_s_barrier();
    COMPUTE(buf);
    __builtin_amdgcn_s_barrier();
    __builtin_amdgcn_sched_barrier(0);
  }
  asm volatile("s_waitcnt vmcnt(0)" ::: "memory");
  __builtin_amdgcn_sched_barrier(0);
  __builtin_amdgcn_s_barrier();
  COMPUTE(1);

  // ---- epilogue: 3 chunks of 16 rows per wave (10 KB wave-private region) ----
  __syncthreads();
  const int which = n0 / kC;
  const int h = ((n0 + wc) % kC) >> 6;             // wave-uniform head (wc in {0,64})

  if (which == 2) {
    bf16* tq = (bf16*)smem + w * 5120;             // 10 KB region, uses 2080 B
    const int tokrow = lr;
    const int dl = lg;
#pragma unroll
    for (int mi = 0; mi < 3; ++mi) {
#pragma unroll
      for (int ni = 0; ni < 4; ++ni)
#pragma unroll
        for (int r = 0; r < 4; ++r)
          tq[(lg * 4 + r) * 65 + ni * 16 + lr] = (bf16)acc[mi][ni][r];
      __builtin_amdgcn_sched_barrier(0);           // keep write->read->overwrite order
      const int m = m0 + wr + mi * 16 + tokrow;
      if (m < kM) {
        const int b = m / kNtok;
        const int tok = m - b * kNtok;
        bf16* vdst = vtb + ((size_t)(b * 12 + h) * 64 + dl) * kTok + tok;
#pragma unroll
        for (int it = 0; it < 16; ++it)
          vdst[(size_t)(it * 4) * kTok] = tq[tokrow * 65 + it * 4 + dl];
      }
      __builtin_amdgcn_sched_barrier(0);
    }
  } else {
    float* tp = (float*)smem + w * 2560;           // 10 KB region, uses 4 KB
    bf16* dst = (which == 0) ? qh : kbq;
    const float sc = (which == 0) ? 0.125f : 1.0f;
    const int c4 = lr * 4;
#pragma unroll
    for (int mi = 0; mi < 3; ++mi) {
#pragma unroll
      for (int ni = 0; ni < 4; ++ni)
#pragma unroll
        for (int r = 0; r < 4; ++r)
          tp[(lg * 4 + r) * 64 + ni * 16 + lr] = acc[mi][ni][r];
      __builtin_amdgcn_sched_barrier(0);
#pragma unroll
      for (int i = 0; i < 4; ++i) {
        const int row = i * 4 + lg;
        const int m = m0 + wr + mi * 16 + row;
        if (m >= kM) continue;
        float4 v4 = *(const float4*)&tp[row * 64 + c4];
        const int b = m / kNtok;
        const int tok = m - b * kNtok;
        float e0 = v4.x, o0 = v4.y, e1 = v4.z, o1 = v4.w;
        if (tok > 0) {
          const int tb = (h * 576 + tok - 1) * 32 + (c4 >> 1);
          float2 cc = *(const float2*)&cosT[tb];
          float2 ss = *(const float2*)&sinT[tb];
          float r0 = e0 * cc.x - o0 * ss.x, i0 = e0 * ss.x + o0 * cc.x;
          float r1 = e1 * cc.y - o1 * ss.y, i1 = e1 * ss.y + o1 * cc.y;
          e0 = r0; o0 = i0; e1 = r1; o1 = i1;
        }
        bf16x4 ov;
        ov[0] = (bf16)(e0 * sc); ov[1] = (bf16)(o0 * sc);
        ov[2] = (bf16)(e1 * sc); ov[3] = (bf16)(o1 * sc);
        *(bf16x4*)(dst + (((size_t)(b * 12 + h)) * kTok + tok) * 64 + c4) = ov;
      }
      __builtin_amdgcn_sched_barrier(0);
    }
  }
}

// ---------------- flash attention: 8 waves, in-register softmax (T12) -----------
// Swapped QK^T: s[ni]=mfma(kf,qf) -> lane (lr,lg) holds P[key=16ni+4lg+r][qrow=lr].
// Stage 1 (shfl_xor 16): pw[n] = pair-block keys 16n+8*(lg>>1)+{0..7}.
// Stage 2 (shfl_xor 32): route pair-blocks across halves; lane (b1,b0) keeps own
// pw[2kc+b1] if b1==b0 else takes partner's. No Ps LDS: 32KB total.
__global__ __launch_bounds__(512, 4) void attn_kernel(
    const bf16* __restrict__ qh, const bf16* __restrict__ kbq, const bf16* __restrict__ vtb,
    bf16* __restrict__ aoh) {
  __shared__ __align__(16) bf16 Ks[2][64 * 64];   // 16 KB
  __shared__ __align__(16) bf16 Vs[2][64 * 64];   // 16 KB
  const int tid = (int)threadIdx.x;
  const int l = tid & 63, w = tid >> 6;           // 8 waves
  const int lr = l & 15, lg = l >> 4;

  const int lid = swz_lid((int)blockIdx.x, 5 * kBH);
  const int bh = lid / 5, qt = lid - bh * 5;      // all 5 q-tiles of a bh -> one XCD
  const int q0 = qt * 128;

  const int srow = w * 8 + (l >> 3);
  const int gch = (l & 7) ^ ((l >> 3) & 7);
  const bf16* kG = kbq + ((size_t)bh * kTok + srow) * 64 + gch * 8;
  const bf16* vG = vtb + ((size_t)bh * 64 + srow) * kTok + gch * 8;

  auto STAGE = [&](int buf, int j0) {
    gl16(kG + (size_t)j0 * 64, &Ks[buf][(w * 8) * 64]);
    gl16(vG + j0, &Vs[buf][(w * 8) * 64]);
  };

  bf16x8 qf[2];
  {
    const bf16* qp = qh + ((size_t)bh * kTok + (q0 + w * 16 + lr)) * 64 + lg * 8;
    qf[0] = *(const bf16x8*)qp;
    qf[1] = *(const bf16x8*)(qp + 32);
  }
  bf16x8 ones;
#pragma unroll
  for (int j = 0; j < 8; ++j) ones[j] = (bf16)1.0f;

  const f32x4 z = {0.f, 0.f, 0.f, 0.f};
  f32x4 o[4];
#pragma unroll
  for (int nf = 0; nf < 4; ++nf) o[nf] = z;
  f32x4 den = z;
  const bool odd = (lg & 1) != 0;       // b0
  const bool hi2 = (lg >> 1) != 0;      // b1

  STAGE(0, 0);
#pragma unroll 1
  for (int jt = 0; jt < 9; ++jt) {              // 9 tiles = keys 0..575 exactly
    const int cur = jt & 1;
    __syncthreads();               // drains vmcnt(0): tile jt DMA done; prev reads done
    if (jt < 8) STAGE(cur ^ 1, (jt + 1) * 64);  // DMA overlaps compute below

    // S^T = K Q^T (swapped operands; lane holds key=16ni+4lg+r, qrow=lr)
    f32x4 s[4];
#pragma unroll
    for (int ni = 0; ni < 4; ++ni) s[ni] = z;
    __builtin_amdgcn_s_setprio(1);
#pragma unroll
    for (int kc = 0; kc < 2; ++kc) {
#pragma unroll
      for (int ni = 0; ni < 4; ++ni) {
        int row = ni * 16 + lr;
        bf16x8 kf = *(const bf16x8*)&Ks[cur][row * 64 + (((kc * 4 + lg) ^ (row & 7)) << 3)];
        s[ni] = __builtin_amdgcn_mfma_f32_16x16x32_bf16(kf, qf[kc], s[ni], 0, 0, 0);
      }
    }
    __builtin_amdgcn_s_setprio(0);

    // exp + pack (explicit casts; element0 = low word): Aw[n]=keys 16n+4lg+{0,1}
    unsigned int Aw[4], Bw[4], Xw[4], Yw[4];
#pragma unroll
    for (int n = 0; n < 4; ++n) {
      bf16x2 pa, pb;
      pa[0] = (bf16)__expf(s[n][0]); pa[1] = (bf16)__expf(s[n][1]);
      pb[0] = (bf16)__expf(s[n][2]); pb[1] = (bf16)__expf(s[n][3]);
      Aw[n] = __builtin_bit_cast(unsigned int, pa);
      Bw[n] = __builtin_bit_cast(unsigned int, pb);
      Xw[n] = __shfl_xor(Aw[n], 16);
      Yw[n] = __shfl_xor(Bw[n], 16);
    }
    // pair-block pw[n] = keys 16n + 8*(lg>>1) + {0..7} at qrow=lr
    unsigned int pw[4][4];
#pragma unroll
    for (int n = 0; n < 4; ++n) {
      pw[n][0] = odd ? Xw[n] : Aw[n];
      pw[n][1] = odd ? Yw[n] : Bw[n];
      pw[n][2] = odd ? Aw[n] : Xw[n];
      pw[n][3] = odd ? Bw[n] : Yw[n];
    }
    // half-exchange via shfl_xor 32: lane needs pw[2kc+b1] from half b0
    bf16x8 pf2[2];
#pragma unroll
    for (int kc = 0; kc < 2; ++kc) {
      u32x4 wv;
#pragma unroll
      for (int i = 0; i < 4; ++i) {
        unsigned int send = hi2 ? pw[2 * kc][i] : pw[2 * kc + 1][i];
        unsigned int recv = __shfl_xor(send, 32);
        unsigned int own = hi2 ? pw[2 * kc + 1][i] : pw[2 * kc][i];
        wv[i] = (hi2 != odd) ? recv : own;
      }
      pf2[kc] = __builtin_bit_cast(bf16x8, wv);
    }

    // O += P V ; den += P 1
    __builtin_amdgcn_s_setprio(1);
#pragma unroll
    for (int kc = 0; kc < 2; ++kc) {
      den = __builtin_amdgcn_mfma_f32_16x16x32_bf16(pf2[kc], ones, den, 0, 0, 0);
#pragma unroll
      for (int nf = 0; nf < 4; ++nf) {
        int row = nf * 16 + lr;
        bf16x8 vf = *(const bf16x8*)&Vs[cur][row * 64 + (((kc * 4 + lg) ^ (row & 7)) << 3)];
        o[nf] = __builtin_amdgcn_mfma_f32_16x16x32_bf16(pf2[kc], vf, o[nf], 0, 0, 0);
      }
    }
    __builtin_amdgcn_s_setprio(0);
  }

  // key 576 (the 577th key) analytic correction: s = q . k576 per q-row
  {
    const bf16* k576 = kbq + ((size_t)bh * kTok + 576) * 64;
    bf16x8 ka = *(const bf16x8*)(k576 + lg * 8);
    bf16x8 kb2 = *(const bf16x8*)(k576 + 32 + lg * 8);
    float part = 0.f;
#pragma unroll
    for (int j = 0; j < 8; ++j)
      part += (float)qf[0][j] * (float)ka[j] + (float)qf[1][j] * (float)kb2[j];
    part += __shfl_xor(part, 16);
    part += __shfl_xor(part, 32);          // s for q-row (w*16 + lr), uniform over lg
    float v576[4];
#pragma unroll
    for (int nf = 0; nf < 4; ++nf)
      v576[nf] = (float)vtb[((size_t)bh * 64 + nf * 16 + lr) * kTok + 576];
#pragma unroll
    for (int r = 0; r < 4; ++r) {
      float p = __expf(__shfl(part, lg * 4 + r));   // row lg*4+r held by lane lr==lg*4+r
      den[r] += p;
#pragma unroll
      for (int nf = 0; nf < 4; ++nf) o[nf][r] += p * v576[nf];
    }
  }

  // epilogue: normalize by den, single bf16 output
  const int b = bh / 12, h = bh % 12;
#pragma unroll
  for (int r = 0; r < 4; ++r) {
    const int tok = q0 + w * 16 + lg * 4 + r;
    if (tok > 576) continue;
    const float inv = 1.0f / den[r];
    const size_t rowb = ((size_t)(b * kNtok + tok)) * kC + h * 64;
#pragma unroll
    for (int nf = 0; nf < 4; ++nf)
      aoh[rowb + nf * 16 + lr] = (bf16)(o[nf][r] * inv);
  }
}

// ---------------- proj GEMM: r7 template, single-A, BK=64, 8 waves --------------
__global__ __launch_bounds__(512, 4) void proj_gemm_kernel(
    const bf16* __restrict__ ah, const bf16* __restrict__ bw,
    const float* __restrict__ bias, float* __restrict__ out) {
  __shared__ __align__(16) char smem[65536];
  bf16* AsB = (bf16*)smem;
  bf16* BsB = (bf16*)(smem + 32768);
  const int tid = (int)threadIdx.x;
  const int l = tid & 63, w = tid >> 6;
  const int lr = l & 15, lg = l >> 4;
  const int wr = (w & 3) * 32, wc = (w >> 2) * 64;

  const int lid = swz_lid((int)blockIdx.x, 6 * 73);
  const int n0 = (lid % 6) * 128, m0 = (lid / 6) * 128;

  const int srow = w * 16 + (l >> 3);
  const int gch = (l & 7) ^ ((l >> 3) & 7);
  const bf16* aG = ah + (size_t)(m0 + srow) * kC + gch * 8;
  const bf16* bG = bw + (size_t)(n0 + srow) * kC + gch * 8;

  f32x4 acc[2][4];
  const f32x4 z = {0.f, 0.f, 0.f, 0.f};
#pragma unroll
  for (int mi = 0; mi < 2; ++mi)
#pragma unroll
    for (int ni = 0; ni < 4; ++ni) acc[mi][ni] = z;

  auto STAGE = [&](int buf, int k0) {
#pragma unroll
    for (int i = 0; i < 2; ++i) {
      gl16(aG + (size_t)i * 8 * kC + k0, &AsB[buf * 8192 + (w * 16 + i * 8) * 64]);
      gl16(bG + (size_t)i * 8 * kC + k0, &BsB[buf * 8192 + (w * 16 + i * 8) * 64]);
    }
  };
  auto COMPUTE = [&](int buf) {
    __builtin_amdgcn_s_setprio(1);
#pragma unroll
    for (int kc = 0; kc < 2; ++kc) {
      bf16x8 af[2], bfr[4];
#pragma unroll
      for (int ni = 0; ni < 4; ++ni) {
        int row = wc + ni * 16 + lr;
        bfr[ni] = *(const bf16x8*)&BsB[buf * 8192 + row * 64 + (((kc * 4 + lg) ^ (lr & 7)) << 3)];
      }
#pragma unroll
      for (int mi = 0; mi < 2; ++mi) {
        int row = wr + mi * 16 + lr;
        af[mi] = *(const bf16x8*)&AsB[buf * 8192 + row * 64 + (((kc * 4 + lg) ^ (lr & 7)) << 3)];
      }
#pragma unroll
      for (int mi = 0; mi < 2; ++mi)
#pragma unroll
        for (int ni = 0; ni < 4; ++ni)
          acc[mi][ni] = __builtin_amdgcn_mfma_f32_16x16x32_bf16(af[mi], bfr[ni], acc[mi][ni], 0, 0, 0);
    }
    __builtin_amdgcn_s_setprio(0);
  };

  STAGE(0, 0);
#pragma unroll 1
  for (int t = 0; t < 11; ++t) {
    const int buf = t & 1;
    STAGE(buf ^ 1, (t + 1) * 64);
    asm volatile("s_waitcnt vmcnt(4)" ::: "memory");
    __builtin_amdgcn_sched_barrier(0);
    __builtin_amdgcn_s_barrier();
    COMPUTE(buf);
    __builtin_amdgcn_s_barrier();
    __builtin_amdgcn_sched_barrier(0);
  }
  asm volatile("s_waitcnt vmcnt(0)" ::: "memory");
  __builtin_amdgcn_sched_barrier(0);
  __builtin_amdgcn_s_barrier();
  COMPUTE(1);

  __syncthreads();
  float* tp = (float*)smem + w * 2048;
#pragma unroll
  for (int mi = 0; mi < 2; ++mi)
#pragma unroll
    for (int ni = 0; ni < 4; ++ni)
#pragma unroll
      for (int r = 0; r < 4; ++r)
        tp[(mi * 16 + lg * 4 + r) * 64 + ni * 16 + lr] = acc[mi][ni][r];

  const int c4 = lr * 4;
  const int ncol = n0 + wc + c4;
  float4 bv = *(const float4*)&bias[ncol];
#pragma unroll
  for (int i = 0; i < 8; ++i) {
    const int row = i * 4 + lg;
    const int m = m0 + wr + row;
    if (m >= kM) continue;
    float4 v4 = *(const float4*)&tp[row * 64 + c4];
    v4.x += bv.x; v4.y += bv.y; v4.z += bv.z; v4.w += bv.w;
    *(float4*)(out + (size_t)m * kC + ncol) = v4;
  }
}

// ---------------- launch ----------------
extern "C" void kernel_launch(void* const* d_in, const int* in_sizes, int n_in,
                              void* d_out, int out_size, void* d_ws, size_t ws_size,
                              hipStream_t stream) {
  const float* x = (const float*)d_in[0];
  const float* qkv_w = (const float*)d_in[1];
  const float* proj_w = (const float*)d_in[2];
  const float* proj_b = (const float*)d_in[3];
  const float* freqs = (const float*)d_in[4];
  float* out = (float*)d_out;

  char* p = (char*)d_ws;
  auto take = [&](size_t bytes) { char* r = p; p += (bytes + 255) & ~(size_t)255; return r; };
  float* cosT = (float*)take(221184 * 4);
  float* sinT = (float*)take(221184 * 4);
  bf16* xb   = (bf16*)take((size_t)kMpadQ * kC * 2);
  bf16* wqb  = (bf16*)take((size_t)2304 * kC * 2);
  bf16* pwb  = (bf16*)take((size_t)kC * kC * 2);
  bf16* qh   = (bf16*)take((size_t)kBH * kTok * 64 * 2);
  bf16* kbq  = (bf16*)take((size_t)kBH * kTok * 64 * 2);
  bf16* vtb  = (bf16*)take((size_t)kBH * 64 * kTok * 2);
  bf16* aoh  = (bf16*)take((size_t)kMpadP * kC * 2);

  prep_kernel<<<3528 + 864 + 288 + 864, 256, 0, stream>>>(
      x, qkv_w, proj_w, freqs, xb, wqb, pwb, cosT, sinT);
  qkv_gemm_kernel<<<dim3(49 * 18), 512, 0, stream>>>(xb, wqb, cosT, sinT, qh, kbq, vtb);
  attn_kernel<<<dim3(5 * kBH), 512, 0, stream>>>(qh, kbq, vtb, aoh);
  proj_gemm_kernel<<<dim3(6 * 73), 512, 0, stream>>>(aoh, pwb, proj_b, out);
}

// Round 9
// 110.464 us; speedup vs baseline: 1.0111x; 1.0111x over previous
//
#include <hip/hip_runtime.h>

// RoPEAttention MI355X round 22 (= round 19 exact, best-measured 110.3us):
//  qkv : 192x128 2-phase BK=64 + fused RoPE + fused V-transpose epilogue (CLOSED:
//        4 structural attempts all >= this; at K-scaled m97-structure rate).
//  attn: 8-wave QBLK=128 LDS-softmax (r21 T12 in-reg variant measured neutral
//        -1.4us worse; this form is the A/B winner).
//  proj/prep: r7 template / BW-floor prep.

typedef __bf16 bf16;
typedef __bf16 bf16x4 __attribute__((ext_vector_type(4)));
typedef __bf16 bf16x8 __attribute__((ext_vector_type(8)));
typedef float f32x4 __attribute__((ext_vector_type(4)));

namespace {
constexpr int kC = 768;
constexpr int kNtok = 577;
constexpr int kM = 16 * kNtok;     // 9232
constexpr int kMpadQ = 9408;       // 49 * 192 (qkv A pad)
constexpr int kMpadP = 9344;       // 73 * 128 (proj A pad)
constexpr int kTok = 640;
constexpr int kBH = 192;
}

typedef __attribute__((address_space(3))) unsigned int as3_u32;
typedef __attribute__((address_space(1))) unsigned int as1_u32;
__device__ __forceinline__ void gl16(const bf16* g, bf16* l) {
  __builtin_amdgcn_global_load_lds((const as1_u32*)g, (as3_u32*)l, 16, 0, 0);
}

// m204 bijective XCD swizzle
__device__ __forceinline__ int swz_lid(int hid, int nwg) {
  int q = nwg >> 3, r = nwg & 7;
  int x = hid & 7, y = hid >> 3;
  int base = (x < r) ? x * (q + 1) : r * (q + 1) + (x - r) * q;
  return base + y;
}

// ---------------- fused prep: conv_x | conv_w(qkv) | conv_w(proj) | rope --------
__global__ __launch_bounds__(256) void prep_kernel(
    const float* __restrict__ x, const float* __restrict__ qkv_w,
    const float* __restrict__ proj_w, const float* __restrict__ freqs,
    bf16* __restrict__ xb, bf16* __restrict__ wqb, bf16* __restrict__ pwb,
    float* __restrict__ cosT, float* __restrict__ sinT) {
  const int bidx = (int)blockIdx.x;
  const int tid = (int)threadIdx.x;
  if (bidx < 3528) {                       // conv_x: kMpadQ*96 chunks of 8
    int idx = bidx * 256 + tid;
    int m = idx / 96, c8 = (idx % 96) * 8;
    bf16x8 o;
    if (m < kM) {
      const float* p = x + (size_t)m * kC + c8;
#pragma unroll
      for (int j = 0; j < 8; ++j) o[j] = (bf16)p[j];
    } else {
#pragma unroll
      for (int j = 0; j < 8; ++j) o[j] = (bf16)0.0f;
    }
    *(bf16x8*)(xb + (size_t)m * kC + c8) = o;
  } else if (bidx < 3528 + 864) {          // conv_w qkv: 2304*768
    int off = ((bidx - 3528) * 256 + tid) * 8;
    bf16x8 o;
#pragma unroll
    for (int j = 0; j < 8; ++j) o[j] = (bf16)qkv_w[off + j];
    *(bf16x8*)(wqb + off) = o;
  } else if (bidx < 3528 + 864 + 288) {    // conv_w proj: 768*768
    int off = ((bidx - 3528 - 864) * 256 + tid) * 8;
    bf16x8 o;
#pragma unroll
    for (int j = 0; j < 8; ++j) o[j] = (bf16)proj_w[off + j];
    *(bf16x8*)(pwb + off) = o;
  } else {                                 // rope table: 12*576*32
    int idx = (bidx - 3528 - 864 - 288) * 256 + tid;
    int f = idx & 31;
    int t = (idx >> 5) % 576;
    int h = idx / (576 * 32);
    float ang = (float)(t % 24) * freqs[h * 32 + f] + (float)(t / 24) * freqs[384 + h * 32 + f];
    float s, c;
    sincosf(ang, &s, &c);
    cosT[idx] = c;
    sinT[idx] = s;
  }
}

// ---------------- qkv GEMM 192x128, 8 waves (4M x 2N, wave 48x64), BK=64 --------
// r7 2-phase counted-vmcnt schedule; 5 gl16/thread per STAGE -> vmcnt(5).
__global__ __launch_bounds__(512, 4) void qkv_gemm_kernel(
    const bf16* __restrict__ xb, const bf16* __restrict__ wb,
    const float* __restrict__ cosT, const float* __restrict__ sinT,
    bf16* __restrict__ qh, bf16* __restrict__ kbq, bf16* __restrict__ vtb) {
  __shared__ __align__(16) char smem[81920];
  bf16* AsB = (bf16*)smem;             // [2][192*64] = 48 KB
  bf16* BsB = (bf16*)(smem + 49152);   // [2][128*64] = 32 KB
  const int tid = (int)threadIdx.x;
  const int l = tid & 63, w = tid >> 6;        // 8 waves
  const int lr = l & 15, lg = l >> 4;
  const int wr = (w & 3) * 48, wc = (w >> 2) * 64;   // wave tile 48x64

  const int lid = swz_lid((int)blockIdx.x, 49 * 18);
  const int n0 = (lid % 18) * 128, m0 = (lid / 18) * 192;

  const int srow = w * 8 + (l >> 3);           // 64 rows per staging pass
  const int gch = (l & 7) ^ ((l >> 3) & 7);    // pre-swizzled global chunk
  const bf16* aG = xb + (size_t)(m0 + srow) * kC + gch * 8;
  const bf16* bG = wb + (size_t)(n0 + srow) * kC + gch * 8;

  f32x4 acc[3][4];
  const f32x4 z = {0.f, 0.f, 0.f, 0.f};
#pragma unroll
  for (int mi = 0; mi < 3; ++mi)
#pragma unroll
    for (int ni = 0; ni < 4; ++ni) acc[mi][ni] = z;

  auto STAGE = [&](int buf, int k0) {
#pragma unroll
    for (int i = 0; i < 3; ++i)
      gl16(aG + (size_t)i * 64 * kC + k0, &AsB[buf * 12288 + (i * 64 + w * 8) * 64]);
#pragma unroll
    for (int j = 0; j < 2; ++j)
      gl16(bG + (size_t)j * 64 * kC + k0, &BsB[buf * 8192 + (j * 64 + w * 8) * 64]);
  };
  auto COMPUTE = [&](int buf) {
    __builtin_amdgcn_s_setprio(1);
#pragma unroll
    for (int kc = 0; kc < 2; ++kc) {
      bf16x8 af[3], bfr[4];
#pragma unroll
      for (int ni = 0; ni < 4; ++ni) {
        int row = wc + ni * 16 + lr;
        bfr[ni] = *(const bf16x8*)&BsB[buf * 8192 + row * 64 + (((kc * 4 + lg) ^ (lr & 7)) << 3)];
      }
#pragma unroll
      for (int mi = 0; mi < 3; ++mi) {
        int row = wr + mi * 16 + lr;
        af[mi] = *(const bf16x8*)&AsB[buf * 12288 + row * 64 + (((kc * 4 + lg) ^ (lr & 7)) << 3)];
      }
#pragma unroll
      for (int mi = 0; mi < 3; ++mi)
#pragma unroll
        for (int ni = 0; ni < 4; ++ni)
          acc[mi][ni] = __builtin_amdgcn_mfma_f32_16x16x32_bf16(af[mi], bfr[ni], acc[mi][ni], 0, 0, 0);
    }
    __builtin_amdgcn_s_setprio(0);
  };

  STAGE(0, 0);
#pragma unroll 1
  for (int t = 0; t < 11; ++t) {
    const int buf = t & 1;
    STAGE(buf ^ 1, (t + 1) * 64);
    asm volatile("s_waitcnt vmcnt(5)" ::: "memory");
    __builtin_amdgcn_sched_barrier(0);
    __builtin_amdgcn_s_barrier();
    COMPUTE(buf);
    __builtin_amdgcn_s_barrier();
    __builtin_amdgcn_sched_barrier(0);
  }
  asm volatile("s_waitcnt vmcnt(0)" ::: "memory");
  __builtin_amdgcn_sched_barrier(0);
  __builtin_amdgcn_s_barrier();
  COMPUTE(1);

  // ---- epilogue: 3 chunks of 16 rows per wave (10 KB wave-private region) ----
  __syncthreads();
  const int which = n0 / kC;
  const int h = ((n0 + wc) % kC) >> 6;             // wave-uniform head (wc in {0,64})

  if (which == 2) {
    bf16* tq = (bf16*)smem + w * 5120;             // 10 KB region, uses 2080 B
    const int tokrow = lr;
    const int dl = lg;
#pragma unroll
    for (int mi = 0; mi < 3; ++mi) {
#pragma unroll
      for (int ni = 0; ni < 4; ++ni)
#pragma unroll
        for (int r = 0; r < 4; ++r)
          tq[(lg * 4 + r) * 65 + ni * 16 + lr] = (bf16)acc[mi][ni][r];
      __builtin_amdgcn_sched_barrier(0);           // keep write->read->overwrite order
      const int m = m0 + wr + mi * 16 + tokrow;
      if (m < kM) {
        const int b = m / kNtok;
        const int tok = m - b * kNtok;
        bf16* vdst = vtb + ((size_t)(b * 12 + h) * 64 + dl) * kTok + tok;
#pragma unroll
        for (int it = 0; it < 16; ++it)
          vdst[(size_t)(it * 4) * kTok] = tq[tokrow * 65 + it * 4 + dl];
      }
      __builtin_amdgcn_sched_barrier(0);
    }
  } else {
    float* tp = (float*)smem + w * 2560;           // 10 KB region, uses 4 KB
    bf16* dst = (which == 0) ? qh : kbq;
    const float sc = (which == 0) ? 0.125f : 1.0f;
    const int c4 = lr * 4;
#pragma unroll
    for (int mi = 0; mi < 3; ++mi) {
#pragma unroll
      for (int ni = 0; ni < 4; ++ni)
#pragma unroll
        for (int r = 0; r < 4; ++r)
          tp[(lg * 4 + r) * 64 + ni * 16 + lr] = acc[mi][ni][r];
      __builtin_amdgcn_sched_barrier(0);
#pragma unroll
      for (int i = 0; i < 4; ++i) {
        const int row = i * 4 + lg;
        const int m = m0 + wr + mi * 16 + row;
        if (m >= kM) continue;
        float4 v4 = *(const float4*)&tp[row * 64 + c4];
        const int b = m / kNtok;
        const int tok = m - b * kNtok;
        float e0 = v4.x, o0 = v4.y, e1 = v4.z, o1 = v4.w;
        if (tok > 0) {
          const int tb = (h * 576 + tok - 1) * 32 + (c4 >> 1);
          float2 cc = *(const float2*)&cosT[tb];
          float2 ss = *(const float2*)&sinT[tb];
          float r0 = e0 * cc.x - o0 * ss.x, i0 = e0 * ss.x + o0 * cc.x;
          float r1 = e1 * cc.y - o1 * ss.y, i1 = e1 * ss.y + o1 * cc.y;
          e0 = r0; o0 = i0; e1 = r1; o1 = i1;
        }
        bf16x4 ov;
        ov[0] = (bf16)(e0 * sc); ov[1] = (bf16)(o0 * sc);
        ov[2] = (bf16)(e1 * sc); ov[3] = (bf16)(o1 * sc);
        *(bf16x4*)(dst + (((size_t)(b * 12 + h)) * kTok + tok) * 64 + c4) = ov;
      }
      __builtin_amdgcn_sched_barrier(0);
    }
  }
}

// ---------------- flash attention: 8 waves, 9 exact K-tiles + key-576 -----------
__global__ __launch_bounds__(512, 8) void attn_kernel(
    const bf16* __restrict__ qh, const bf16* __restrict__ kbq, const bf16* __restrict__ vtb,
    bf16* __restrict__ aoh) {
  __shared__ __align__(16) bf16 Ks[2][64 * 64];   // 16 KB
  __shared__ __align__(16) bf16 Vs[2][64 * 64];   // 16 KB
  __shared__ __align__(16) bf16 Ps[8][16 * 64];   // 16 KB
  const int tid = (int)threadIdx.x;
  const int l = tid & 63, w = tid >> 6;           // 8 waves
  const int lr = l & 15, lg = l >> 4;

  const int lid = swz_lid((int)blockIdx.x, 5 * kBH);
  const int bh = lid / 5, qt = lid - bh * 5;      // all 5 q-tiles of a bh -> one XCD
  const int q0 = qt * 128;

  const int srow = w * 8 + (l >> 3);
  const int gch = (l & 7) ^ ((l >> 3) & 7);
  const bf16* kG = kbq + ((size_t)bh * kTok + srow) * 64 + gch * 8;
  const bf16* vG = vtb + ((size_t)bh * 64 + srow) * kTok + gch * 8;

  auto STAGE = [&](int buf, int j0) {
    gl16(kG + (size_t)j0 * 64, &Ks[buf][(w * 8) * 64]);
    gl16(vG + j0, &Vs[buf][(w * 8) * 64]);
  };

  bf16x8 qf[2];
  {
    const bf16* qp = qh + ((size_t)bh * kTok + (q0 + w * 16 + lr)) * 64 + lg * 8;
    qf[0] = *(const bf16x8*)qp;
    qf[1] = *(const bf16x8*)(qp + 32);
  }
  bf16x8 ones;
#pragma unroll
  for (int j = 0; j < 8; ++j) ones[j] = (bf16)1.0f;

  const f32x4 z = {0.f, 0.f, 0.f, 0.f};
  f32x4 o[4];
#pragma unroll
  for (int nf = 0; nf < 4; ++nf) o[nf] = z;
  f32x4 den = z;

  STAGE(0, 0);
#pragma unroll 1
  for (int jt = 0; jt < 9; ++jt) {              // 9 tiles = keys 0..575 exactly
    const int cur = jt & 1;
    __syncthreads();               // drains vmcnt(0): tile jt DMA done; prev reads done
    if (jt < 8) STAGE(cur ^ 1, (jt + 1) * 64);  // DMA overlaps compute below

    // S = Q K^T
    f32x4 s[4];
#pragma unroll
    for (int ni = 0; ni < 4; ++ni) s[ni] = z;
    __builtin_amdgcn_s_setprio(1);
#pragma unroll
    for (int kc = 0; kc < 2; ++kc) {
#pragma unroll
      for (int ni = 0; ni < 4; ++ni) {
        int row = ni * 16 + lr;
        bf16x8 kf = *(const bf16x8*)&Ks[cur][row * 64 + (((kc * 4 + lg) ^ (row & 7)) << 3)];
        s[ni] = __builtin_amdgcn_mfma_f32_16x16x32_bf16(qf[kc], kf, s[ni], 0, 0, 0);
      }
    }
    __builtin_amdgcn_s_setprio(0);

    // P = exp(S)  (no masking needed: all 64 keys of every tile are valid)
#pragma unroll
    for (int ni = 0; ni < 4; ++ni)
#pragma unroll
      for (int r = 0; r < 4; ++r) {
        float p = __expf(s[ni][r]);
        int prow = lg * 4 + r;
        int pcol = ni * 16 + lr;
        Ps[w][prow * 64 + ((((pcol >> 3) ^ (prow & 7)) & 7) << 3) + (pcol & 7)] = (bf16)p;
      }

    // O += P V ; den += P 1
    __builtin_amdgcn_s_setprio(1);
#pragma unroll
    for (int kc = 0; kc < 2; ++kc) {
      bf16x8 pf = *(const bf16x8*)&Ps[w][lr * 64 + (((kc * 4 + lg) ^ (lr & 7)) << 3)];
      den = __builtin_amdgcn_mfma_f32_16x16x32_bf16(pf, ones, den, 0, 0, 0);
#pragma unroll
      for (int nf = 0; nf < 4; ++nf) {
        int row = nf * 16 + lr;
        bf16x8 vf = *(const bf16x8*)&Vs[cur][row * 64 + (((kc * 4 + lg) ^ (row & 7)) << 3)];
        o[nf] = __builtin_amdgcn_mfma_f32_16x16x32_bf16(pf, vf, o[nf], 0, 0, 0);
      }
    }
    __builtin_amdgcn_s_setprio(0);
  }

  // key 576 (the 577th key) analytic correction: s = q . k576 per q-row
  {
    const bf16* k576 = kbq + ((size_t)bh * kTok + 576) * 64;
    bf16x8 ka = *(const bf16x8*)(k576 + lg * 8);
    bf16x8 kb2 = *(const bf16x8*)(k576 + 32 + lg * 8);
    float part = 0.f;
#pragma unroll
    for (int j = 0; j < 8; ++j)
      part += (float)qf[0][j] * (float)ka[j] + (float)qf[1][j] * (float)kb2[j];
    part += __shfl_xor(part, 16);
    part += __shfl_xor(part, 32);          // s for q-row (w*16 + lr), uniform over lg
    float v576[4];
#pragma unroll
    for (int nf = 0; nf < 4; ++nf)
      v576[nf] = (float)vtb[((size_t)bh * 64 + nf * 16 + lr) * kTok + 576];
#pragma unroll
    for (int r = 0; r < 4; ++r) {
      float p = __expf(__shfl(part, lg * 4 + r));   // row lg*4+r held by lane lr==lg*4+r
      den[r] += p;
#pragma unroll
      for (int nf = 0; nf < 4; ++nf) o[nf][r] += p * v576[nf];
    }
  }

  // epilogue: normalize by den, single bf16 output
  const int b = bh / 12, h = bh % 12;
#pragma unroll
  for (int r = 0; r < 4; ++r) {
    const int tok = q0 + w * 16 + lg * 4 + r;
    if (tok > 576) continue;
    const float inv = 1.0f / den[r];
    const size_t rowb = ((size_t)(b * kNtok + tok)) * kC + h * 64;
#pragma unroll
    for (int nf = 0; nf < 4; ++nf)
      aoh[rowb + nf * 16 + lr] = (bf16)(o[nf][r] * inv);
  }
}

// ---------------- proj GEMM: r7 template, single-A, BK=64, 8 waves --------------
__global__ __launch_bounds__(512, 4) void proj_gemm_kernel(
    const bf16* __restrict__ ah, const bf16* __restrict__ bw,
    const float* __restrict__ bias, float* __restrict__ out) {
  __shared__ __align__(16) char smem[65536];
  bf16* AsB = (bf16*)smem;
  bf16* BsB = (bf16*)(smem + 32768);
  const int tid = (int)threadIdx.x;
  const int l = tid & 63, w = tid >> 6;
  const int lr = l & 15, lg = l >> 4;
  const int wr = (w & 3) * 32, wc = (w >> 2) * 64;

  const int lid = swz_lid((int)blockIdx.x, 6 * 73);
  const int n0 = (lid % 6) * 128, m0 = (lid / 6) * 128;

  const int srow = w * 16 + (l >> 3);
  const int gch = (l & 7) ^ ((l >> 3) & 7);
  const bf16* aG = ah + (size_t)(m0 + srow) * kC + gch * 8;
  const bf16* bG = bw + (size_t)(n0 + srow) * kC + gch * 8;

  f32x4 acc[2][4];
  const f32x4 z = {0.f, 0.f, 0.f, 0.f};
#pragma unroll
  for (int mi = 0; mi < 2; ++mi)
#pragma unroll
    for (int ni = 0; ni < 4; ++ni) acc[mi][ni] = z;

  auto STAGE = [&](int buf, int k0) {
#pragma unroll
    for (int i = 0; i < 2; ++i) {
      gl16(aG + (size_t)i * 8 * kC + k0, &AsB[buf * 8192 + (w * 16 + i * 8) * 64]);
      gl16(bG + (size_t)i * 8 * kC + k0, &BsB[buf * 8192 + (w * 16 + i * 8) * 64]);
    }
  };
  auto COMPUTE = [&](int buf) {
    __builtin_amdgcn_s_setprio(1);
#pragma unroll
    for (int kc = 0; kc < 2; ++kc) {
      bf16x8 af[2], bfr[4];
#pragma unroll
      for (int ni = 0; ni < 4; ++ni) {
        int row = wc + ni * 16 + lr;
        bfr[ni] = *(const bf16x8*)&BsB[buf * 8192 + row * 64 + (((kc * 4 + lg) ^ (lr & 7)) << 3)];
      }
#pragma unroll
      for (int mi = 0; mi < 2; ++mi) {
        int row = wr + mi * 16 + lr;
        af[mi] = *(const bf16x8*)&AsB[buf * 8192 + row * 64 + (((kc * 4 + lg) ^ (lr & 7)) << 3)];
      }
#pragma unroll
      for (int mi = 0; mi < 2; ++mi)
#pragma unroll
        for (int ni = 0; ni < 4; ++ni)
          acc[mi][ni] = __builtin_amdgcn_mfma_f32_16x16x32_bf16(af[mi], bfr[ni], acc[mi][ni], 0, 0, 0);
    }
    __builtin_amdgcn_s_setprio(0);
  };

  STAGE(0, 0);
#pragma unroll 1
  for (int t = 0; t < 11; ++t) {
    const int buf = t & 1;
    STAGE(buf ^ 1, (t + 1) * 64);
    asm volatile("s_waitcnt vmcnt(4)" ::: "memory");
    __builtin_amdgcn_sched_barrier(0);
    __builtin_amdgcn_s_barrier();
    COMPUTE(buf);
    __builtin_amdgcn_s_barrier();
    __builtin_amdgcn_sched_barrier(0);
  }
  asm volatile("s_waitcnt vmcnt(0)" ::: "memory");
  __builtin_amdgcn_sched_barrier(0);
  __builtin_amdgcn_s_barrier();
  COMPUTE(1);

  __syncthreads();
  float* tp = (float*)smem + w * 2048;
#pragma unroll
  for (int mi = 0; mi < 2; ++mi)
#pragma unroll
    for (int ni = 0; ni < 4; ++ni)
#pragma unroll
      for (int r = 0; r < 4; ++r)
        tp[(mi * 16 + lg * 4 + r) * 64 + ni * 16 + lr] = acc[mi][ni][r];

  const int c4 = lr * 4;
  const int ncol = n0 + wc + c4;
  float4 bv = *(const float4*)&bias[ncol];
#pragma unroll
  for (int i = 0; i < 8; ++i) {
    const int row = i * 4 + lg;
    const int m = m0 + wr + row;
    if (m >= kM) continue;
    float4 v4 = *(const float4*)&tp[row * 64 + c4];
    v4.x += bv.x; v4.y += bv.y; v4.z += bv.z; v4.w += bv.w;
    *(float4*)(out + (size_t)m * kC + ncol) = v4;
  }
}

// ---------------- launch ----------------
extern "C" void kernel_launch(void* const* d_in, const int* in_sizes, int n_in,
                              void* d_out, int out_size, void* d_ws, size_t ws_size,
                              hipStream_t stream) {
  const float* x = (const float*)d_in[0];
  const float* qkv_w = (const float*)d_in[1];
  const float* proj_w = (const float*)d_in[2];
  const float* proj_b = (const float*)d_in[3];
  const float* freqs = (const float*)d_in[4];
  float* out = (float*)d_out;

  char* p = (char*)d_ws;
  auto take = [&](size_t bytes) { char* r = p; p += (bytes + 255) & ~(size_t)255; return r; };
  float* cosT = (float*)take(221184 * 4);
  float* sinT = (float*)take(221184 * 4);
  bf16* xb   = (bf16*)take((size_t)kMpadQ * kC * 2);
  bf16* wqb  = (bf16*)take((size_t)2304 * kC * 2);
  bf16* pwb  = (bf16*)take((size_t)kC * kC * 2);
  bf16* qh   = (bf16*)take((size_t)kBH * kTok * 64 * 2);
  bf16* kbq  = (bf16*)take((size_t)kBH * kTok * 64 * 2);
  bf16* vtb  = (bf16*)take((size_t)kBH * 64 * kTok * 2);
  bf16* aoh  = (bf16*)take((size_t)kMpadP * kC * 2);

  prep_kernel<<<3528 + 864 + 288 + 864, 256, 0, stream>>>(
      x, qkv_w, proj_w, freqs, xb, wqb, pwb, cosT, sinT);
  qkv_gemm_kernel<<<dim3(49 * 18), 512, 0, stream>>>(xb, wqb, cosT, sinT, qh, kbq, vtb);
  attn_kernel<<<dim3(5 * kBH), 512, 0, stream>>>(qh, kbq, vtb, aoh);
  proj_gemm_kernel<<<dim3(6 * 73), 512, 0, stream>>>(aoh, pwb, proj_b, out);
}